// Round 20
// baseline (279.591 us; speedup 1.0000x reference)
//
#include <hip/hip_runtime.h>
#include <hip/hip_bf16.h>

typedef __hip_bfloat16 bf16;
typedef __attribute__((ext_vector_type(8))) short short8;
typedef __attribute__((ext_vector_type(4))) short short4v;
typedef __attribute__((ext_vector_type(4))) float f32x4;

#define DIMC 2048
#define TSEQ 2048
#define NB 2
#define KVH 4
#define NH 16
#define HD 128
#define KVD 512
// softmax scale folded into Wq, in log2 domain: 1/sqrt(128) * log2(e)
#define QSCALE 0.12751744f

#if __has_builtin(__builtin_amdgcn_exp2f)
#define EXP2(x) __builtin_amdgcn_exp2f(x)   // raw v_exp_f32, no libm fixup
#else
#define EXP2(x) exp2f(x)
#endif

__device__ __forceinline__ float fmax3(float a, float b, float c) {
  return fmaxf(fmaxf(a, b), c);   // clang fuses to v_max3_f32
}

__device__ __forceinline__ void mfma16(f32x4& acc, short8 a, short8 b) {
  acc = __builtin_amdgcn_mfma_f32_16x16x32_bf16(a, b, acc, 0, 0, 0);
}

__device__ __forceinline__ void gload_lds16(const bf16* g, bf16* l) {
  __builtin_amdgcn_global_load_lds(
      (const __attribute__((address_space(1))) void*)g,
      (__attribute__((address_space(3))) void*)l, 16, 0, 0);
}

// XOR-swizzle a within-row element index (16B-slot granularity, bf16 elems).
__device__ __forceinline__ int swz(int row, int col) {
  return col ^ ((row & 7) << 3);
}

// ---- all 4 weight transposes + x:f32->bf16 in ONE dispatch ----
// y<32: Wq (scaled); y<40: Wk; y<48: Wv; y<80: Wo; y>=80: f2b convert of x.
__global__ __launch_bounds__(256) void transpose_all(const float* __restrict__ Wq,
                                                     const float* __restrict__ Wk,
                                                     const float* __restrict__ Wv,
                                                     const float* __restrict__ Wo,
                                                     const float* __restrict__ x,
                                                     bf16* __restrict__ WT3,
                                                     bf16* __restrict__ WoT,
                                                     bf16* __restrict__ xb) {
  const int y = blockIdx.y;
  if (y >= 80) {  // f2b: 1024 blocks x 8 float4/thread
    long base = (((long)(y - 80) * 32 + blockIdx.x) * 2048) + threadIdx.x;
#pragma unroll
    for (int j = 0; j < 8; ++j) {
      long i = base + j * 256;
      const f32x4 v = *(const f32x4*)(x + i * 4);
      union { short4v s; bf16 h[4]; } u;
#pragma unroll
      for (int k = 0; k < 4; ++k) u.h[k] = __float2bfloat16(v[k]);
      *(short4v*)(xb + i * 4) = u.s;
    }
    return;
  }
  __shared__ bf16 tile[64][72];
  const float* in;
  bf16* out;
  int C, rb, cb;
  float scale = 1.0f;
  if (y < 32) {
    in = Wq; out = WT3; C = 2048;
    rb = y * 64; cb = blockIdx.x * 64; scale = QSCALE;
  } else if (y < 40) {
    in = Wk; out = WT3 + (long)2048 * DIMC; C = 512;
    rb = blockIdx.x * 64; cb = (y - 32) * 64;
  } else if (y < 48) {
    in = Wv; out = WT3 + (long)2560 * DIMC; C = 512;
    rb = blockIdx.x * 64; cb = (y - 40) * 64;
  } else {
    in = Wo; out = WoT; C = 2048;
    rb = (y - 48) * 64; cb = blockIdx.x * 64;
  }
  int tx = threadIdx.x & 63, ty = threadIdx.x >> 6;
  for (int i = ty; i < 64; i += 4)
    tile[i][tx] = __float2bfloat16(in[(long)(rb + i) * C + cb + tx] * scale);
  __syncthreads();
  for (int i = ty; i < 64; i += 4)
    out[(long)(cb + i) * DIMC + rb + tx] = tile[tx][i];
}

// XCD-aware bijective remap (T1). Requires total blocks % 8 == 0.
#define XCD_REMAP(NX)                                                          \
  const int flat_ = blockIdx.y * (NX) + blockIdx.x;                            \
  const int tot_ = (NX) * gridDim.y;                                           \
  const int log_ = (flat_ & 7) * (tot_ >> 3) + (flat_ >> 3);                   \
  const long m0 = (long)(log_ / (NX)) * 128, n0 = (long)(log_ % (NX)) * 128;

// ---------------- shared GEMM K-loop body (128x128 tile, BK=32) ----------------
// R17-proven m97 structure (R18's BK=64+swizzle was a measured regression).
#define GEMM_BODY(A_, Bt_, K_)                                                  \
  const int tid = threadIdx.x;                                                  \
  const int lane = tid & 63, wid = tid >> 6;                                    \
  const int wm = (wid >> 1) * 64, wn = (wid & 1) * 64;                          \
  f32x4 acc[4][4] = {};                                                         \
  const int srow = lane >> 2, scol = (lane & 3) * 8;                            \
  const bf16* Ag = A_ + (m0 + srow) * (long)K_ + scol;                          \
  const bf16* Bg = Bt_ + (n0 + srow) * (long)K_ + scol;                         \
  for (int k0 = 0; k0 < K_; k0 += 32) {                                         \
    for (int p = 0; p < 2; ++p) {                                               \
      int rr = p * 64 + wid * 16;                                               \
      gload_lds16(Ag + (long)rr * K_ + k0, As + rr * 32);                       \
      gload_lds16(Bg + (long)rr * K_ + k0, Bs + rr * 32);                       \
    }                                                                           \
    __syncthreads();                                                            \
    const int ko = (lane >> 4) * 8;                                             \
    short8 af[4], bq[4];                                                        \
    _Pragma("unroll") for (int i = 0; i < 4; ++i) {                             \
      af[i] = *(const short8*)(As + (wm + i * 16 + (lane & 15)) * 32 + ko);     \
      bq[i] = *(const short8*)(Bs + (wn + i * 16 + (lane & 15)) * 32 + ko);     \
    }                                                                           \
    _Pragma("unroll") for (int i = 0; i < 4; ++i)                               \
      _Pragma("unroll") for (int j = 0; j < 4; ++j)                             \
        mfma16(acc[i][j], af[i], bq[j]);                                        \
    __syncthreads();                                                            \
  }                                                                             \
  const int cr = (lane >> 4) * 4, cc = lane & 15;

// ------------- fused QKV GEMM: A[4096][2048] x WT3[3072][2048]^T -------------
__global__ __launch_bounds__(256) void gemm_qkv(const bf16* __restrict__ A,
                                                const bf16* __restrict__ Bt,
                                                bf16* __restrict__ qp,
                                                bf16* __restrict__ kp,
                                                bf16* __restrict__ vT) {
  __shared__ bf16 As[128 * 32];
  __shared__ bf16 Bs[128 * 32];
  XCD_REMAP(24)
  GEMM_BODY(A, Bt, 2048)
#pragma unroll
  for (int i = 0; i < 4; ++i)
#pragma unroll
    for (int j = 0; j < 4; ++j)
#pragma unroll
      for (int r = 0; r < 4; ++r) {
        long m = m0 + wm + i * 16 + cr + r;
        long n = n0 + wn + j * 16 + cc;
        float val = acc[i][j][r];
        if (n0 < 2048) {
          qp[m * DIMC + n] = __float2bfloat16(val);
        } else if (n0 < 2560) {
          kp[m * KVD + (n - 2048)] = __float2bfloat16(val);
        } else {
          long nn = n - 2560;
          long z = (m >> 11) * 4 + (nn >> 7);
          vT[z * (HD * (long)TSEQ) + (nn & 127) * (long)TSEQ + (m & 2047)] =
              __float2bfloat16(val);
        }
      }
}

// ------------- O GEMM: fp32 output -------------
__global__ __launch_bounds__(256) void gemm_out(const bf16* __restrict__ A,
                                                const bf16* __restrict__ Bt,
                                                float* __restrict__ C) {
  __shared__ bf16 As[128 * 32];
  __shared__ bf16 Bs[128 * 32];
  XCD_REMAP(16)
  GEMM_BODY(A, Bt, 2048)
#pragma unroll
  for (int i = 0; i < 4; ++i)
#pragma unroll
    for (int j = 0; j < 4; ++j)
#pragma unroll
      for (int r = 0; r < 4; ++r) {
        long m = m0 + wm + i * 16 + cr + r;
        long n = n0 + wn + j * 16 + cc;
        C[m * DIMC + n] = acc[i][j][r];
      }
}

// ---------------- flash attention fwd: KVBLK=128, single-buffered ----------------
// R20: halve per-q-row tile-visits 32->16 (R15 measured ~0.4us fixed cost per
// visit). Single-buffer K/V (32+32KB -> 2 blocks/CU); 2 barriers x 16 tiles =
// same 32 barrier-waits as R17's 32x1. V phys slot (4c2+lg+row)&15; k-bijection
// s=(2c2+(j>>2))*16+lg*4+(j&3) matched on A(V-read) and B(pb) sides.
__global__ __launch_bounds__(256, 2) void attn_fwd(const bf16* __restrict__ Qp,
                                                   const bf16* __restrict__ Kp,
                                                   const bf16* __restrict__ Vt,
                                                   bf16* __restrict__ AO) {
  __shared__ bf16 Ks[128 * 128];   // [s][d], XOR-swizzled
  __shared__ bf16 Vts[128 * 128];  // [d][s'-permuted], 16 slots, row-rotated
  const int tid = threadIdx.x;
  const int lane = tid & 63, wid = tid >> 6;   // wid 0..3
  const int h = blockIdx.y, b = blockIdx.z;
  const int kv = h >> 2;
  const int t0 = blockIdx.x * 128;
  const int lr = lane & 15, lg = lane >> 4;

  short8 aq[2][4];
#pragma unroll
  for (int f = 0; f < 2; ++f) {
    const bf16* qrow =
        Qp + ((long)(b * TSEQ + t0 + wid * 32 + f * 16 + lr)) * DIMC + h * HD + lg * 8;
#pragma unroll
    for (int c = 0; c < 4; ++c) aq[f][c] = *(const short8*)(qrow + c * 32);
  }
  f32x4 o[2][8] = {};
  float mrun[2] = {-1e30f, -1e30f}, lrun[2] = {0.f, 0.f};  // lrun: per-lane partial

  const bf16* Kg = Kp + (long)b * TSEQ * KVD + kv * HD;
  const bf16* Vg = Vt + ((long)(b * KVH + kv)) * HD * TSEQ;

  // staging ownership (256 threads): K row tid>>1 (0..127), col half (tid&1)*64;
  // V d-row tid>>1, s half (tid&1)*64. 8 short8 each.
  const int kr = tid >> 1, kh = (tid & 1) * 64;
  short8 kreg[8], vreg[8];
#pragma unroll
  for (int p = 0; p < 8; ++p) {
    kreg[p] = *(const short8*)(Kg + (long)kr * KVD + kh + 8 * p);
    vreg[p] = *(const short8*)(Vg + (long)kr * TSEQ + kh + 8 * p);
  }

  for (int s0 = 0; s0 < TSEQ; s0 += 128) {
    // write this tile's regs -> LDS
#pragma unroll
    for (int p = 0; p < 8; ++p) {
      *(short8*)(Ks + kr * 128 + swz(kr, kh + 8 * p)) = kreg[p];
      // V chunk: s-base S0 = kh+8p; t=S0>>4 (c2=t>>1, hi=t&1), lg0=(S0>>2)&3
      int S0 = kh + 8 * p;
      int t = S0 >> 4, lg0 = (S0 >> 2) & 3;   // lg0 in {0,2}
      union { short8 v8; short4v q[2]; } u;
      u.v8 = vreg[p];
      int base4 = 4 * (t >> 1);
      int sl1 = (base4 + lg0 + kr) & 15;
      int sl2 = (base4 + lg0 + 1 + kr) & 15;
      int hf = (t & 1) * 4;
      *(short4v*)(Vts + kr * 128 + sl1 * 8 + hf) = u.q[0];
      *(short4v*)(Vts + kr * 128 + sl2 * 8 + hf) = u.q[1];
    }
    __syncthreads();  // writes visible before reads
    if (s0 + 128 < TSEQ) {  // prefetch next tile; lands under compute
#pragma unroll
      for (int p = 0; p < 8; ++p) {
        kreg[p] = *(const short8*)(Kg + (long)(s0 + 128 + kr) * KVD + kh + 8 * p);
        vreg[p] = *(const short8*)(Vg + (long)kr * TSEQ + s0 + 128 + kh + 8 * p);
      }
    }

    // S^T = K Q^T : each kf read feeds both q-fragments; sf 0..7
    f32x4 sacc[2][8] = {};
    __builtin_amdgcn_s_setprio(1);
#pragma unroll
    for (int sf = 0; sf < 8; ++sf)
#pragma unroll
      for (int c = 0; c < 4; ++c) {
        int row = sf * 16 + lr;
        short8 kf = *(const short8*)(Ks + row * 128 + swz(row, c * 32 + lg * 8));
        mfma16(sacc[0][sf], kf, aq[0][c]);
        mfma16(sacc[1][sf], kf, aq[1][c]);
      }
    __builtin_amdgcn_s_setprio(0);

    // online softmax (base-2), per-lane scalar state, per fragment
    union { short8 s; bf16 h[8]; } pb[2][4];
#pragma unroll
    for (int f = 0; f < 2; ++f) {
      float tmax = sacc[f][0][0];
#pragma unroll
      for (int sf = 0; sf < 8; ++sf)
#pragma unroll
        for (int r = 0; r < 4; ++r) tmax = fmaxf(tmax, sacc[f][sf][r]);
      tmax = fmaxf(tmax, __shfl_xor(tmax, 16));
      tmax = fmaxf(tmax, __shfl_xor(tmax, 32));
      if (__any(tmax > mrun[f] + 8.0f)) {  // defer-max: P bounded by 2^8
        float mnew = fmaxf(mrun[f], tmax);
        float fac = EXP2(mrun[f] - mnew);   // uniform within 4-lane q-row group
        mrun[f] = mnew;
        lrun[f] *= fac;
#pragma unroll
        for (int df = 0; df < 8; ++df) o[f][df] *= fac;
      }
      float ps = 0.f;
#pragma unroll
      for (int c2 = 0; c2 < 4; ++c2)
#pragma unroll
        for (int r = 0; r < 4; ++r) {
          float v0 = EXP2(sacc[f][2 * c2][r] - mrun[f]);      // hi=0
          float v1 = EXP2(sacc[f][2 * c2 + 1][r] - mrun[f]);  // hi=1
          ps += v0 + v1;
          pb[f][c2].h[r] = __float2bfloat16(v0);
          pb[f][c2].h[4 + r] = __float2bfloat16(v1);
        }
      lrun[f] += ps;   // shuffles deferred to epilogue
    }

    // O^T += V^T P : one b128 per (c2,df); slot (4c2+lg+row)&15
    __builtin_amdgcn_s_setprio(1);
#pragma unroll
    for (int c2 = 0; c2 < 4; ++c2) {
#pragma unroll
      for (int df = 0; df < 8; ++df) {
        int row = df * 16 + lr;
        short8 vf = *(const short8*)(Vts + row * 128 + ((4 * c2 + lg + row) & 15) * 8);
        mfma16(o[0][df], vf, pb[0][c2].s);
        mfma16(o[1][df], vf, pb[1][c2].s);
      }
    }
    __builtin_amdgcn_s_setprio(0);
    __syncthreads();  // all reads done before next tile's overwrite
  }

  // epilogue: reduce per-lane lrun partials across the 4-lane q-row group
#pragma unroll
  for (int f = 0; f < 2; ++f) {
    lrun[f] += __shfl_xor(lrun[f], 16);
    lrun[f] += __shfl_xor(lrun[f], 32);
  }

#pragma unroll
  for (int f = 0; f < 2; ++f) {
    float inv = 1.0f / lrun[f];
    bf16* obase =
        AO + ((long)(b * TSEQ + t0 + wid * 32 + f * 16 + lr)) * DIMC + h * HD + lg * 4;
#pragma unroll
    for (int df = 0; df < 8; ++df) {
      union { short4v s; bf16 h[4]; } ov;
#pragma unroll
      for (int r = 0; r < 4; ++r) ov.h[r] = __float2bfloat16(o[f][df][r] * inv);
      *(short4v*)(obase + df * 16) = ov.s;
    }
  }
}

extern "C" void kernel_launch(void* const* d_in, const int* in_sizes, int n_in,
                              void* d_out, int out_size, void* d_ws, size_t ws_size,
                              hipStream_t stream) {
  const float* x  = (const float*)d_in[0];
  const float* Wq = (const float*)d_in[1];
  const float* Wk = (const float*)d_in[2];
  const float* Wv = (const float*)d_in[3];
  const float* Wo = (const float*)d_in[4];
  float* out = (float*)d_out;
  bf16* ws = (bf16*)d_ws;

  bf16* xb  = ws;                 // [4096][2048] x (bf16); later reused as ao
  bf16* WT3 = xb + 8388608;       // [3072][2048] WqT|WkT|WvT
  bf16* WoT = WT3 + 6291456;      // [2048][2048]
  bf16* qp  = WoT + 4194304;      // [4096][2048]
  bf16* kp  = qp + 8388608;       // [4096][512]
  bf16* vT  = kp + 2097152;       // [8][128][2048]
  // total 31.5M bf16 = 62.9 MB

  transpose_all<<<dim3(32, 112), 256, 0, stream>>>(Wq, Wk, Wv, Wo, x, WT3, WoT, xb);

  gemm_qkv<<<dim3(24, 32), 256, 0, stream>>>(xb, WT3, qp, kp, vT);

  bf16* ao = xb;  // x dead after QKV gemm
  attn_fwd<<<dim3(16, 16, 2), 256, 0, stream>>>(qp, kp, vT, ao);

  gemm_out<<<dim3(16, 32), 256, 0, stream>>>(ao, WoT, out);
}

// Round 21
// 218.917 us; speedup vs baseline: 1.2772x; 1.2772x over previous
//
#include <hip/hip_runtime.h>
#include <hip/hip_bf16.h>

typedef __hip_bfloat16 bf16;
typedef __attribute__((ext_vector_type(8))) short short8;
typedef __attribute__((ext_vector_type(4))) short short4v;
typedef __attribute__((ext_vector_type(4))) float f32x4;

#define DIMC 2048
#define TSEQ 2048
#define NB 2
#define KVH 4
#define NH 16
#define HD 128
#define KVD 512
// softmax scale folded into Wq, in log2 domain: 1/sqrt(128) * log2(e)
#define QSCALE 0.12751744f

#if __has_builtin(__builtin_amdgcn_exp2f)
#define EXP2(x) __builtin_amdgcn_exp2f(x)   // raw v_exp_f32, no libm fixup
#else
#define EXP2(x) exp2f(x)
#endif

__device__ __forceinline__ float fmax3(float a, float b, float c) {
  return fmaxf(fmaxf(a, b), c);   // clang fuses to v_max3_f32
}

__device__ __forceinline__ void mfma16(f32x4& acc, short8 a, short8 b) {
  acc = __builtin_amdgcn_mfma_f32_16x16x32_bf16(a, b, acc, 0, 0, 0);
}

__device__ __forceinline__ void gload_lds16(const bf16* g, bf16* l) {
  __builtin_amdgcn_global_load_lds(
      (const __attribute__((address_space(1))) void*)g,
      (__attribute__((address_space(3))) void*)l, 16, 0, 0);
}

// XOR-swizzle a within-row element index (16B-slot granularity, bf16 elems).
__device__ __forceinline__ int swz(int row, int col) {
  return col ^ ((row & 7) << 3);
}

// ---- all 4 weight transposes + x:f32->bf16 in ONE dispatch ----
// y<32: Wq (scaled); y<40: Wk; y<48: Wv; y<80: Wo; y>=80: f2b convert of x.
__global__ __launch_bounds__(256) void transpose_all(const float* __restrict__ Wq,
                                                     const float* __restrict__ Wk,
                                                     const float* __restrict__ Wv,
                                                     const float* __restrict__ Wo,
                                                     const float* __restrict__ x,
                                                     bf16* __restrict__ WT3,
                                                     bf16* __restrict__ WoT,
                                                     bf16* __restrict__ xb) {
  const int y = blockIdx.y;
  if (y >= 80) {  // f2b: 1024 blocks x 8 float4/thread
    long base = (((long)(y - 80) * 32 + blockIdx.x) * 2048) + threadIdx.x;
#pragma unroll
    for (int j = 0; j < 8; ++j) {
      long i = base + j * 256;
      const f32x4 v = *(const f32x4*)(x + i * 4);
      union { short4v s; bf16 h[4]; } u;
#pragma unroll
      for (int k = 0; k < 4; ++k) u.h[k] = __float2bfloat16(v[k]);
      *(short4v*)(xb + i * 4) = u.s;
    }
    return;
  }
  __shared__ bf16 tile[64][72];
  const float* in;
  bf16* out;
  int C, rb, cb;
  float scale = 1.0f;
  if (y < 32) {
    in = Wq; out = WT3; C = 2048;
    rb = y * 64; cb = blockIdx.x * 64; scale = QSCALE;
  } else if (y < 40) {
    in = Wk; out = WT3 + (long)2048 * DIMC; C = 512;
    rb = blockIdx.x * 64; cb = (y - 32) * 64;
  } else if (y < 48) {
    in = Wv; out = WT3 + (long)2560 * DIMC; C = 512;
    rb = blockIdx.x * 64; cb = (y - 40) * 64;
  } else {
    in = Wo; out = WoT; C = 2048;
    rb = (y - 48) * 64; cb = blockIdx.x * 64;
  }
  int tx = threadIdx.x & 63, ty = threadIdx.x >> 6;
  for (int i = ty; i < 64; i += 4)
    tile[i][tx] = __float2bfloat16(in[(long)(rb + i) * C + cb + tx] * scale);
  __syncthreads();
  for (int i = ty; i < 64; i += 4)
    out[(long)(cb + i) * DIMC + rb + tx] = tile[tx][i];
}

// XCD-aware bijective remap (T1). Requires total blocks % 8 == 0.
#define XCD_REMAP(NX)                                                          \
  const int flat_ = blockIdx.y * (NX) + blockIdx.x;                            \
  const int tot_ = (NX) * gridDim.y;                                           \
  const int log_ = (flat_ & 7) * (tot_ >> 3) + (flat_ >> 3);                   \
  const long m0 = (long)(log_ / (NX)) * 128, n0 = (long)(log_ % (NX)) * 128;

// ---------------- shared GEMM K-loop body (128x128 tile, BK=32) ----------------
// R17-proven m97 structure (R18's BK=64+swizzle was a measured regression).
#define GEMM_BODY(A_, Bt_, K_)                                                  \
  const int tid = threadIdx.x;                                                  \
  const int lane = tid & 63, wid = tid >> 6;                                    \
  const int wm = (wid >> 1) * 64, wn = (wid & 1) * 64;                          \
  f32x4 acc[4][4] = {};                                                         \
  const int srow = lane >> 2, scol = (lane & 3) * 8;                            \
  const bf16* Ag = A_ + (m0 + srow) * (long)K_ + scol;                          \
  const bf16* Bg = Bt_ + (n0 + srow) * (long)K_ + scol;                         \
  for (int k0 = 0; k0 < K_; k0 += 32) {                                         \
    for (int p = 0; p < 2; ++p) {                                               \
      int rr = p * 64 + wid * 16;                                               \
      gload_lds16(Ag + (long)rr * K_ + k0, As + rr * 32);                       \
      gload_lds16(Bg + (long)rr * K_ + k0, Bs + rr * 32);                       \
    }                                                                           \
    __syncthreads();                                                            \
    const int ko = (lane >> 4) * 8;                                             \
    short8 af[4], bq[4];                                                        \
    _Pragma("unroll") for (int i = 0; i < 4; ++i) {                             \
      af[i] = *(const short8*)(As + (wm + i * 16 + (lane & 15)) * 32 + ko);     \
      bq[i] = *(const short8*)(Bs + (wn + i * 16 + (lane & 15)) * 32 + ko);     \
    }                                                                           \
    _Pragma("unroll") for (int i = 0; i < 4; ++i)                               \
      _Pragma("unroll") for (int j = 0; j < 4; ++j)                             \
        mfma16(acc[i][j], af[i], bq[j]);                                        \
    __syncthreads();                                                            \
  }                                                                             \
  const int cr = (lane >> 4) * 4, cc = lane & 15;

// ------------- fused QKV GEMM: A[4096][2048] x WT3[3072][2048]^T -------------
__global__ __launch_bounds__(256) void gemm_qkv(const bf16* __restrict__ A,
                                                const bf16* __restrict__ Bt,
                                                bf16* __restrict__ qp,
                                                bf16* __restrict__ kp,
                                                bf16* __restrict__ vT) {
  __shared__ bf16 As[128 * 32];
  __shared__ bf16 Bs[128 * 32];
  XCD_REMAP(24)
  GEMM_BODY(A, Bt, 2048)
#pragma unroll
  for (int i = 0; i < 4; ++i)
#pragma unroll
    for (int j = 0; j < 4; ++j)
#pragma unroll
      for (int r = 0; r < 4; ++r) {
        long m = m0 + wm + i * 16 + cr + r;
        long n = n0 + wn + j * 16 + cc;
        float val = acc[i][j][r];
        if (n0 < 2048) {
          qp[m * DIMC + n] = __float2bfloat16(val);
        } else if (n0 < 2560) {
          kp[m * KVD + (n - 2048)] = __float2bfloat16(val);
        } else {
          long nn = n - 2560;
          long z = (m >> 11) * 4 + (nn >> 7);
          vT[z * (HD * (long)TSEQ) + (nn & 127) * (long)TSEQ + (m & 2047)] =
              __float2bfloat16(val);
        }
      }
}

// ------------- O GEMM: fp32 output -------------
__global__ __launch_bounds__(256) void gemm_out(const bf16* __restrict__ A,
                                                const bf16* __restrict__ Bt,
                                                float* __restrict__ C) {
  __shared__ bf16 As[128 * 32];
  __shared__ bf16 Bs[128 * 32];
  XCD_REMAP(16)
  GEMM_BODY(A, Bt, 2048)
#pragma unroll
  for (int i = 0; i < 4; ++i)
#pragma unroll
    for (int j = 0; j < 4; ++j)
#pragma unroll
      for (int r = 0; r < 4; ++r) {
        long m = m0 + wm + i * 16 + cr + r;
        long n = n0 + wn + j * 16 + cc;
        C[m * DIMC + n] = acc[i][j][r];
      }
}

// ---------------- flash attention fwd (R17/R19 structure — best measured) ----------------
__global__ __launch_bounds__(256, 2) void attn_fwd(const bf16* __restrict__ Qp,
                                                   const bf16* __restrict__ Kp,
                                                   const bf16* __restrict__ Vt,
                                                   bf16* __restrict__ AO) {
  __shared__ bf16 Ks[2][64 * 128];    // [s][d], XOR-swizzled
  __shared__ bf16 Vts[2][128 * 64];   // [d][s'-permuted], row-rotated slots
  const int tid = threadIdx.x;
  const int lane = tid & 63, wid = tid >> 6;   // wid 0..3
  const int h = blockIdx.y, b = blockIdx.z;
  const int kv = h >> 2;
  const int t0 = blockIdx.x * 128;
  const int lr = lane & 15, lg = lane >> 4;

  short8 aq[2][4];
#pragma unroll
  for (int f = 0; f < 2; ++f) {
    const bf16* qrow =
        Qp + ((long)(b * TSEQ + t0 + wid * 32 + f * 16 + lr)) * DIMC + h * HD + lg * 8;
#pragma unroll
    for (int c = 0; c < 4; ++c) aq[f][c] = *(const short8*)(qrow + c * 32);
  }
  f32x4 o[2][8] = {};
  float mrun[2] = {-1e30f, -1e30f}, lrun[2] = {0.f, 0.f};  // lrun: per-lane partial

  const bf16* Kg = Kp + (long)b * TSEQ * KVD + kv * HD;
  const bf16* Vg = Vt + ((long)(b * KVH + kv)) * HD * TSEQ;

  const int krow = tid >> 2;
  const int vrow = tid >> 1;
  short8 kreg[2][2], vreg[2][2];
#pragma unroll
  for (int s = 0; s < 2; ++s)
#pragma unroll
    for (int p = 0; p < 2; ++p) {
      kreg[s][p] = *(const short8*)(Kg + (long)krow * KVD + (2 * (tid & 3) + s) * 16 + p * 8);
      vreg[s][p] = *(const short8*)(Vg + (long)vrow * TSEQ + (2 * (tid & 1) + s) * 16 + 8 * p);
    }

  for (int s0 = 0; s0 < TSEQ; s0 += 64) {
    const int buf = (s0 >> 6) & 1;
    bf16* Kb = Ks[buf];
    bf16* Vb = Vts[buf];
#pragma unroll
    for (int s = 0; s < 2; ++s)
#pragma unroll
      for (int p = 0; p < 2; ++p) {
        int kc0 = (2 * (tid & 3) + s) * 16;
        *(short8*)(Kb + krow * 128 + swz(krow, kc0 + p * 8)) = kreg[s][p];
        int va = 2 * (tid & 1) + s;
        union { short8 v8; short4v q[2]; } u;
        u.v8 = vreg[s][p];
        int sl1 = (4 * (va >> 1) + 2 * p + vrow) & 7;       // q=2p piece
        int sl2 = (4 * (va >> 1) + 2 * p + 1 + vrow) & 7;   // q=2p+1 piece
        int hf = (va & 1) * 4;
        *(short4v*)(Vb + vrow * 64 + sl1 * 8 + hf) = u.q[0];
        *(short4v*)(Vb + vrow * 64 + sl2 * 8 + hf) = u.q[1];
      }
    __syncthreads();  // single barrier per tile (double-buffered)
    if (s0 + 64 < TSEQ) {  // prefetch next tile; lands under compute
#pragma unroll
      for (int s = 0; s < 2; ++s)
#pragma unroll
        for (int p = 0; p < 2; ++p) {
          kreg[s][p] = *(const short8*)(Kg + (long)(s0 + 64 + krow) * KVD +
                                        (2 * (tid & 3) + s) * 16 + p * 8);
          vreg[s][p] = *(const short8*)(Vg + (long)vrow * TSEQ + s0 + 64 +
                                        (2 * (tid & 1) + s) * 16 + 8 * p);
        }
    }

    // S^T = K Q^T : each kf read feeds both q-fragments
    f32x4 sacc[2][4] = {};
    __builtin_amdgcn_s_setprio(1);
#pragma unroll
    for (int sf = 0; sf < 4; ++sf)
#pragma unroll
      for (int c = 0; c < 4; ++c) {
        int row = sf * 16 + lr;
        short8 kf = *(const short8*)(Kb + row * 128 + swz(row, c * 32 + lg * 8));
        mfma16(sacc[0][sf], kf, aq[0][c]);
        mfma16(sacc[1][sf], kf, aq[1][c]);
      }
    __builtin_amdgcn_s_setprio(0);

    // online softmax (base-2), per-lane scalar state, per fragment
    union { short8 s; bf16 h[8]; } pb[2][2];
#pragma unroll
    for (int f = 0; f < 2; ++f) {
      float tmax = fmaxf(sacc[f][0][0], sacc[f][0][1]);
      tmax = fmax3(tmax, sacc[f][0][2], sacc[f][0][3]);
      tmax = fmax3(tmax, sacc[f][1][0], sacc[f][1][1]);
      tmax = fmax3(tmax, sacc[f][1][2], sacc[f][1][3]);
      tmax = fmax3(tmax, sacc[f][2][0], sacc[f][2][1]);
      tmax = fmax3(tmax, sacc[f][2][2], sacc[f][2][3]);
      tmax = fmax3(tmax, sacc[f][3][0], sacc[f][3][1]);
      tmax = fmax3(tmax, sacc[f][3][2], sacc[f][3][3]);
      tmax = fmaxf(tmax, __shfl_xor(tmax, 16));
      tmax = fmaxf(tmax, __shfl_xor(tmax, 32));
      if (__any(tmax > mrun[f] + 8.0f)) {  // defer-max: P bounded by 2^8
        float mnew = fmaxf(mrun[f], tmax);
        float fac = EXP2(mrun[f] - mnew);   // uniform within 4-lane q-row group
        mrun[f] = mnew;
        lrun[f] *= fac;
#pragma unroll
        for (int df = 0; df < 8; ++df) o[f][df] *= fac;
      }
      float p4[4][4];
      float ps = 0.f;
#pragma unroll
      for (int sf = 0; sf < 4; ++sf)
#pragma unroll
        for (int r = 0; r < 4; ++r) {
          float pv = EXP2(sacc[f][sf][r] - mrun[f]);
          p4[sf][r] = pv;
          ps += pv;
        }
      lrun[f] += ps;   // shuffles deferred to epilogue
#pragma unroll
      for (int c2 = 0; c2 < 2; ++c2)
#pragma unroll
        for (int r = 0; r < 4; ++r) {
          pb[f][c2].h[r] = __float2bfloat16(p4[2 * c2][r]);
          pb[f][c2].h[4 + r] = __float2bfloat16(p4[2 * c2 + 1][r]);
        }
    }

    // O^T += V^T P : each vf read feeds both fragments
    __builtin_amdgcn_s_setprio(1);
#pragma unroll
    for (int c2 = 0; c2 < 2; ++c2) {
#pragma unroll
      for (int df = 0; df < 8; ++df) {
        int row = df * 16 + lr;
        short8 vf = *(const short8*)(Vb + row * 64 + ((4 * c2 + lg + row) & 7) * 8);
        mfma16(o[0][df], vf, pb[0][c2].s);
        mfma16(o[1][df], vf, pb[1][c2].s);
      }
    }
    __builtin_amdgcn_s_setprio(0);
  }

  // epilogue: reduce per-lane lrun partials across the 4-lane q-row group
#pragma unroll
  for (int f = 0; f < 2; ++f) {
    lrun[f] += __shfl_xor(lrun[f], 16);
    lrun[f] += __shfl_xor(lrun[f], 32);
  }

#pragma unroll
  for (int f = 0; f < 2; ++f) {
    float inv = 1.0f / lrun[f];
    bf16* obase =
        AO + ((long)(b * TSEQ + t0 + wid * 32 + f * 16 + lr)) * DIMC + h * HD + lg * 4;
#pragma unroll
    for (int df = 0; df < 8; ++df) {
      union { short4v s; bf16 h[4]; } ov;
#pragma unroll
      for (int r = 0; r < 4; ++r) ov.h[r] = __float2bfloat16(o[f][df][r] * inv);
      *(short4v*)(obase + df * 16) = ov.s;
    }
  }
}

extern "C" void kernel_launch(void* const* d_in, const int* in_sizes, int n_in,
                              void* d_out, int out_size, void* d_ws, size_t ws_size,
                              hipStream_t stream) {
  const float* x  = (const float*)d_in[0];
  const float* Wq = (const float*)d_in[1];
  const float* Wk = (const float*)d_in[2];
  const float* Wv = (const float*)d_in[3];
  const float* Wo = (const float*)d_in[4];
  float* out = (float*)d_out;
  bf16* ws = (bf16*)d_ws;

  bf16* xb  = ws;                 // [4096][2048] x (bf16); later reused as ao
  bf16* WT3 = xb + 8388608;       // [3072][2048] WqT|WkT|WvT
  bf16* WoT = WT3 + 6291456;      // [2048][2048]
  bf16* qp  = WoT + 4194304;      // [4096][2048]
  bf16* kp  = qp + 8388608;       // [4096][512]
  bf16* vT  = kp + 2097152;       // [8][128][2048]
  // total 31.5M bf16 = 62.9 MB

  transpose_all<<<dim3(32, 112), 256, 0, stream>>>(Wq, Wk, Wv, Wo, x, WT3, WoT, xb);

  gemm_qkv<<<dim3(24, 32), 256, 0, stream>>>(xb, WT3, qp, kp, vT);

  bf16* ao = xb;  // x dead after QKV gemm
  attn_fwd<<<dim3(16, 16, 2), 256, 0, stream>>>(qp, kp, vT, ao);

  gemm_out<<<dim3(16, 32), 256, 0, stream>>>(ao, WoT, out);
}